// Round 10
// baseline (379.188 us; speedup 1.0000x reference)
//
#include <hip/hip_runtime.h>
#include <hip/hip_bf16.h>

// HypergraphGNN on MI355X (gfx950).
// B=4 P=8 N=E=2000 IN=16 HID=128 NL=3 MULT=4. All f32 inputs; internal bf16 MFMA.
//
// Round-10: revert to the round-6 bf16 pipeline (fp8 shelved: scale drift
// broke saturated-sign outputs). New lever: in-block split-K. 512 threads =
// 2 groups x 4 waves; group g computes the SAME 128x128 tile over K-half
// [g*1024, g*1024+1024), BK=32, own 16KB dbuf (LDS 64KB total -> 2 blocks/CU
// = 16 waves/CU, double the TLP of round 6 which was grid-limited at 8).
// Schedule per group = proven round-6 skeleton (static dbuf, counted vmcnt(4),
// setprio MFMA cluster, round-3-proven BK=32 swizzle). Epilogue: g1 dumps f32
// acc to LDS (aliases dead dbufs), g0 adds (exact f32) then runs the
// unchanged round-6 stage-2 + WN/WT epilogue; g1 keeps barrier parity.

typedef __attribute__((ext_vector_type(8))) short bf16x8;
typedef __attribute__((ext_vector_type(4))) float f32x4;

#define GLL16(gp, lp) __builtin_amdgcn_global_load_lds(                      \
    (const __attribute__((address_space(1))) void*)(gp),                     \
    (__attribute__((address_space(3))) void*)(lp), 16, 0, 0)

__device__ __forceinline__ unsigned short f2bf(float v) {
  __hip_bfloat16 h = __float2bfloat16(v);
  return __builtin_bit_cast(unsigned short, h);
}
__device__ __forceinline__ float bf2f(unsigned short u) {
  unsigned int x = ((unsigned int)u) << 16;
  return __builtin_bit_cast(float, x);
}

// ---------------------------------------------------------------------------
// H f32 -> Hb (straight) + HTb (transposed), bf16, padded 2000->2048 w/ zeros
__global__ void convH_k(const float* __restrict__ H,
                        unsigned short* __restrict__ Hb,
                        unsigned short* __restrict__ HTb) {
  int b  = blockIdx.z;
  int n0 = blockIdx.y * 32, e0 = blockIdx.x * 32;
  __shared__ float t[32][33];
  int tx = threadIdx.x & 31, ty = threadIdx.x >> 5;
  for (int r = ty; r < 32; r += 8) {
    int n = n0 + r, e = e0 + tx;
    float v = (n < 2000 && e < 2000) ? H[((long)b * 2000 + n) * 2000 + e] : 0.f;
    t[r][tx] = v;
    Hb[((long)b * 2048 + n) * 2048 + e] = f2bf(v);
  }
  __syncthreads();
  for (int r = ty; r < 32; r += 8) {
    HTb[((long)b * 2048 + (e0 + r)) * 2048 + (n0 + tx)] = f2bf(t[tx][r]);
  }
}

// generic f32 [R][C] -> bf16 [C][R]
__global__ void transposeW_k(const float* __restrict__ src,
                             unsigned short* __restrict__ dst, int R, int C) {
  __shared__ float t[32][33];
  int c0 = blockIdx.x * 32, r0 = blockIdx.y * 32;
  int tx = threadIdx.x & 31, ty = threadIdx.x >> 5;
  for (int rr = ty; rr < 32; rr += 8) {
    int rI = r0 + rr, cI = c0 + tx;
    t[rr][tx] = (rI < R && cI < C) ? src[(long)rI * C + cI] : 0.f;
  }
  __syncthreads();
  for (int rr = ty; rr < 32; rr += 8) {
    int cO = c0 + rr, rO = r0 + tx;
    if (cO < C && rO < R) dst[(long)cO * R + rO] = f2bf(t[tx][rr]);
  }
}

// x0 = nf @ W_in (K=16). Tile: 128 nodes x 128 dims per block.
__global__ __launch_bounds__(256) void x0_k(
    const float* __restrict__ nf, const float* __restrict__ Win,
    unsigned short* __restrict__ xb, unsigned short* __restrict__ xTb) {
  __shared__ float nfs[128][16];
  __shared__ float wins[2048];
  __shared__ unsigned short xt[128][136];

  int bp = blockIdx.y;
  int n0 = blockIdx.x * 128;
  int tid = threadIdx.x;

  {
    int r = tid >> 1, c = (tid & 1) * 8;
    int n = n0 + r;
    float4 v0 = make_float4(0.f, 0.f, 0.f, 0.f), v1 = v0;
    if (n < 2000) {
      const float* src = nf + ((long)bp * 2000 + n) * 16 + c;
      v0 = *(const float4*)src;
      v1 = *(const float4*)(src + 4);
    }
    *(float4*)&nfs[r][c]     = v0;
    *(float4*)&nfs[r][c + 4] = v1;
  }
  {
    int base = tid * 8;
    float4 a = *(const float4*)(Win + base);
    float4 b = *(const float4*)(Win + base + 4);
    *(float4*)&wins[base]     = a;
    *(float4*)&wins[base + 4] = b;
  }
  __syncthreads();

  int d = tid & 127, half = tid >> 7;
  float wcol[16];
#pragma unroll
  for (int k = 0; k < 16; k++) wcol[k] = wins[k * 128 + d];

  unsigned short* xtRow = xTb + ((long)bp * 128 + d) * 2048 + n0 + half * 64;
#pragma unroll
  for (int oct = 0; oct < 8; oct++) {
    bf16x8 pk;
#pragma unroll
    for (int j = 0; j < 8; j++) {
      int nl = half * 64 + oct * 8 + j;
      float v = 0.f;
#pragma unroll
      for (int k = 0; k < 16; k++) v += nfs[nl][k] * wcol[k];
      unsigned short bits = f2bf(v);
      pk[j] = (short)bits;
      xt[nl][d] = bits;
    }
    *(bf16x8*)(xtRow + oct * 8) = pk;
  }
  __syncthreads();

  {
    int r = tid >> 1, c0 = (tid & 1) * 64;
    unsigned short* dst = xb + ((long)bp * 2048 + n0 + r) * 128 + c0;
#pragma unroll
    for (int i = 0; i < 8; i++) {
      bf16x8 v = *(const bf16x8*)&xt[r][c0 + i * 8];
      *(bf16x8*)(dst + i * 8) = v;
    }
  }
}

// wf = W2 @ Wdec  (512x128 @ 128 -> 512)
__global__ void wfuse_k(const float* __restrict__ W2, const float* __restrict__ Wdec,
                        float* __restrict__ wf) {
  int i = blockIdx.x * 256 + threadIdx.x;
  if (i < 512) {
    float s = 0.f;
#pragma unroll 8
    for (int j = 0; j < 128; j++) s += W2[i * 128 + j] * Wdec[j];
    wf[i] = s;
  }
}

// ---------------------------------------------------------------------------
// Fused heavy GEMM, split-K in-block: 512 thr = 2 groups x 4 waves. Group g:
// acc_g = A[m0..m0+128][g*K/2 .. +K/2] @ BT^T, BK=32, own 16KB dbuf.
// Then acc = acc0 + acc1 (f32 via LDS), out = relu(acc @ W), Wt bf16 global.
// Writes Cn and/or Ct. Grid: 512 blocks 1-D XCD-swizzled.
template <int WN, int WT>
__global__ __launch_bounds__(512, 4) void gemm_fused(
    const unsigned short* __restrict__ A, int lda, long strideA, int aDiv,
    const unsigned short* __restrict__ BT, int ldbt, long strideBT,
    const unsigned short* __restrict__ Wt,
    unsigned short* __restrict__ Cn, int ldc, long strideCn,
    unsigned short* __restrict__ Ct, int ldct, long strideCt, int K) {
  // XCD-aware bijective decode: XCD c = wgid&7 owns orig range [c*64, c*64+64)
  int wgid = blockIdx.x;
  int orig = (wgid & 7) * 64 + (wgid >> 3);
  int mblk = orig & 15;
  int bz   = orig >> 4;
  A  += (long)(bz / aDiv) * strideA;
  BT += (long)bz * strideBT;
  int m0 = mblk * 128;

  // 64 KB LDS: group g dbuf at shorts [g*16384, g*16384+16384) =
  //   2 buffers x (A 4096 | B 4096) shorts (16KB each buffer).
  // Epilogue aliases: f32 acc exchange (64KB) then Gs bf16 (lower 32KB).
  __shared__ unsigned short smem[32768];

  int tid  = threadIdx.x;
  int grp  = tid >> 8;        // 0,1: K-half
  int gtid = tid & 255;
  int lane = tid & 63;
  int wig  = (tid >> 6) & 3;  // wave within group
  int wr   = wig >> 1, wc = wig & 1;
  int fr   = lane & 15;       // frag row (A) / col (B,C)
  int fg   = lane >> 4;       // k-chunk (inputs) / row-subgroup (C/D)

  int kbase = grp * (K >> 1);
  int nt = (K >> 1) >> 5;     // 32 K-tiles of BK=32 per group

  // staging: 512 chunks of 16B per operand per tile; thread handles 2.
  // LDS linear; global chunk = slot ^ ((row>>1)&3)  [round-3 proven, <=2-way]
  int ch0 = gtid, ch1 = gtid + 256;
  int r0_ = ch0 >> 2, gc0 = (ch0 & 3) ^ ((r0_ >> 1) & 3);
  int r1_ = ch1 >> 2, gc1 = (ch1 & 3) ^ ((r1_ >> 1) & 3);
  const unsigned short* Ag0 = A + (long)(m0 + r0_) * lda + kbase + gc0 * 8;
  const unsigned short* Ag1 = A + (long)(m0 + r1_) * lda + kbase + gc1 * 8;
  const unsigned short* Bg0 = BT + (long)r0_ * ldbt + kbase + gc0 * 8;
  const unsigned short* Bg1 = BT + (long)r1_ * ldbt + kbase + gc1 * 8;
  unsigned short* db = smem + grp * 16384;

#define STAGE(sel, tk) do {                                                  \
    int _k = (tk) * 32;                                                      \
    GLL16(Ag0 + _k, db + (sel) * 8192 + ch0 * 8);                            \
    GLL16(Ag1 + _k, db + (sel) * 8192 + ch1 * 8);                            \
    GLL16(Bg0 + _k, db + (sel) * 8192 + 4096 + ch0 * 8);                     \
    GLL16(Bg1 + _k, db + (sel) * 8192 + 4096 + ch1 * 8);                     \
  } while (0)

  f32x4 acc[4][4] = {};
  const int cIdx = (fg ^ ((fr >> 1) & 3)) * 8;  // lane-constant frag swizzle

#define COMPUTE(sel) do {                                                    \
    const unsigned short* As_ = db + (sel) * 8192;                           \
    const unsigned short* Bs_ = As_ + 4096;                                  \
    bf16x8 af[4], bv[4];                                                     \
    _Pragma("unroll")                                                        \
    for (int m = 0; m < 4; m++)                                              \
      af[m] = *(const bf16x8*)&As_[(wr * 64 + m * 16 + fr) * 32 + cIdx];     \
    _Pragma("unroll")                                                        \
    for (int n = 0; n < 4; n++)                                              \
      bv[n] = *(const bf16x8*)&Bs_[(wc * 64 + n * 16 + fr) * 32 + cIdx];     \
    __builtin_amdgcn_s_setprio(1);                                           \
    _Pragma("unroll")                                                        \
    for (int m = 0; m < 4; m++)                                              \
      _Pragma("unroll")                                                      \
      for (int n = 0; n < 4; n++)                                            \
        acc[m][n] = __builtin_amdgcn_mfma_f32_16x16x32_bf16(af[m], bv[n],    \
                                                            acc[m][n], 0, 0, 0); \
    __builtin_amdgcn_s_setprio(0);                                           \
  } while (0)

#define VMW(n) asm volatile("s_waitcnt vmcnt(" #n ")" ::: "memory")
#define BARR __builtin_amdgcn_s_barrier()
#define SCH0 __builtin_amdgcn_sched_barrier(0)

  STAGE(0, 0);
  int t = 0;
  for (; t + 2 < nt; t += 2) {
    STAGE(1, t + 1);
    VMW(4); BARR; SCH0;   // tile t landed; t+1 in flight
    COMPUTE(0);
    BARR;                 // buf0 free
    STAGE(0, t + 2);
    VMW(4); BARR; SCH0;   // tile t+1 landed; t+2 in flight
    COMPUTE(1);
    BARR;                 // buf1 free
  }
  STAGE(1, nt - 1);
  VMW(4); BARR; SCH0;
  COMPUTE(0);
  BARR;
  VMW(0); BARR; SCH0;
  COMPUTE(1);
#undef STAGE
#undef COMPUTE

  // ---- split-K reduction: g1 -> LDS f32, g0 adds (exact f32 sum) ----
  float* Lf = (float*)smem;  // 128x128 f32 = 64KB, aliases both dbufs
  __syncthreads();           // all dbuf reads done
  if (grp == 1) {
#pragma unroll
    for (int m = 0; m < 4; m++)
#pragma unroll
      for (int n = 0; n < 4; n++) {
        int rowb = wr * 64 + m * 16 + fg * 4;
        int col  = wc * 64 + n * 16 + fr;
#pragma unroll
        for (int r = 0; r < 4; r++) Lf[(rowb + r) * 128 + col] = acc[m][n][r];
      }
  }
  __syncthreads();
  if (grp == 0) {
#pragma unroll
    for (int m = 0; m < 4; m++)
#pragma unroll
      for (int n = 0; n < 4; n++) {
        int rowb = wr * 64 + m * 16 + fg * 4;
        int col  = wc * 64 + n * 16 + fr;
#pragma unroll
        for (int r = 0; r < 4; r++) acc[m][n][r] += Lf[(rowb + r) * 128 + col];
      }
  }
  __syncthreads();           // f32 reads done; lower 32KB reusable as Gs

  // ---- stage-1 acc -> Gs bf16 row-major 128x128, chunk swizzled (g0) ----
  unsigned short* Gs = smem;
  if (grp == 0) {
#pragma unroll
    for (int m = 0; m < 4; m++) {
#pragma unroll
      for (int n = 0; n < 4; n++) {
        int rowb = wr * 64 + m * 16 + fg * 4;
        int col  = wc * 64 + n * 16 + fr;
        int ch = col >> 3, ci = col & 7;
#pragma unroll
        for (int r = 0; r < 4; r++) {
          int row = rowb + r;
          Gs[row * 128 + ((ch ^ (row & 7)) * 8) + ci] = f2bf(acc[m][n][r]);
        }
      }
    }
  }
  __syncthreads();

  // ---- stage 2 (g0): out = relu(G @ W); A=Gs, B=Wt global (L2-hot) ----
  f32x4 acc2[4][4] = {};
  if (grp == 0) {
#pragma unroll
    for (int kk = 0; kk < 4; kk++) {
      bf16x8 a2[4], b2[4];
#pragma unroll
      for (int m = 0; m < 4; m++) {
        int row = wr * 64 + m * 16 + fr;
        int c = kk * 4 + fg;
        a2[m] = *(const bf16x8*)&Gs[row * 128 + ((c ^ (fr & 7)) * 8)];
      }
#pragma unroll
      for (int n = 0; n < 4; n++) {
        int row = wc * 64 + n * 16 + fr;
        b2[n] = *(const bf16x8*)&Wt[row * 128 + (kk * 4 + fg) * 8];
      }
#pragma unroll
      for (int m = 0; m < 4; m++)
#pragma unroll
        for (int n = 0; n < 4; n++)
          acc2[m][n] = __builtin_amdgcn_mfma_f32_16x16x32_bf16(a2[m], b2[n], acc2[m][n], 0, 0, 0);
    }

    if (WN) {
#pragma unroll
      for (int m = 0; m < 4; m++) {
#pragma unroll
        for (int n = 0; n < 4; n++) {
          int rowb = m0 + wr * 64 + m * 16 + fg * 4;
          int col  = wc * 64 + n * 16 + fr;
          unsigned short* p = Cn + bz * strideCn + (long)rowb * ldc + col;
          p[0]       = f2bf(fmaxf(acc2[m][n][0], 0.f));
          p[ldc]     = f2bf(fmaxf(acc2[m][n][1], 0.f));
          p[2 * ldc] = f2bf(fmaxf(acc2[m][n][2], 0.f));
          p[3 * ldc] = f2bf(fmaxf(acc2[m][n][3], 0.f));
        }
      }
    }
  }

  if (WT) {
    __syncthreads();  // g0's Gs reads done before GsT overwrite
    unsigned short* GsT = smem;
    if (grp == 0) {
#pragma unroll
      for (int m = 0; m < 4; m++) {
#pragma unroll
        for (int n = 0; n < 4; n++) {
          int rowb = wr * 64 + m * 16 + fg * 4;
          int col  = wc * 64 + n * 16 + fr;
          int chunk = rowb >> 3;
          ushort4 pk;
          pk.x = f2bf(fmaxf(acc2[m][n][0], 0.f));
          pk.y = f2bf(fmaxf(acc2[m][n][1], 0.f));
          pk.z = f2bf(fmaxf(acc2[m][n][2], 0.f));
          pk.w = f2bf(fmaxf(acc2[m][n][3], 0.f));
          *(ushort4*)&GsT[col * 128 + ((chunk ^ (col & 7)) * 8) + (rowb & 7)] = pk;
        }
      }
    }
    __syncthreads();
    if (grp == 0) {
      unsigned short* CtB = Ct + bz * strideCt + m0;
#pragma unroll
      for (int i = 0; i < 8; i++) {
        int s = i * 256 + gtid;
        int col = s >> 4, slot = s & 15;
        int l = slot ^ (col & 7);  // logical row-chunk
        bf16x8 v = *(const bf16x8*)&GsT[col * 128 + slot * 8];
        *(bf16x8*)(CtB + (long)col * ldct + l * 8) = v;
      }
    }
  }
}

// ---------------------------------------------------------------------------
// Fused MLP: out[row] = 10*tanh( (sum_i relu(x@W1)[row][i]*wf[i]) / sqrt(128) )
__global__ __launch_bounds__(256) void mlp_k(
    const unsigned short* __restrict__ X,    // [65536][128] bf16 (padded rows)
    const unsigned short* __restrict__ W1T,  // [512][128] bf16
    const float* __restrict__ wf,            // [512]
    float* __restrict__ out) {
  __shared__ unsigned short Xs[128 * 128];
  __shared__ unsigned short Bs[128 * 128];
  __shared__ float rowacc[128];

  int tid  = threadIdx.x;
  int lane = tid & 63;
  int w    = tid >> 6, wr = w >> 1, wc = w & 1;
  int fr   = lane & 15, fg = lane >> 4;
  long m0  = (long)blockIdx.x * 128;

#pragma unroll
  for (int i = 0; i < 8; i++) {
    int s = i * 256 + tid;
    int r = s >> 4, c = (s & 15) ^ (r & 7);
    GLL16(X + (m0 + r) * 128 + c * 8, (unsigned short*)Xs + s * 8);
  }
  if (tid < 128) rowacc[tid] = 0.f;

  float rs[4][4] = {};

  for (int nb = 0; nb < 4; nb++) {
#pragma unroll
    for (int i = 0; i < 8; i++) {
      int s = i * 256 + tid;
      int r = s >> 4, c = (s & 15) ^ (r & 7);
      GLL16(W1T + (long)(nb * 128 + r) * 128 + c * 8, (unsigned short*)Bs + s * 8);
    }
    __syncthreads();

    f32x4 acc[4][4] = {};
#pragma unroll
    for (int kk = 0; kk < 4; kk++) {
      bf16x8 a2[4], b2[4];
#pragma unroll
      for (int m = 0; m < 4; m++) {
        int row = wr * 64 + m * 16 + fr;
        int c = kk * 4 + fg;
        a2[m] = *(const bf16x8*)&Xs[row * 128 + ((c ^ (row & 7)) * 8)];
      }
#pragma unroll
      for (int n = 0; n < 4; n++) {
        int row = wc * 64 + n * 16 + fr;
        int c = kk * 4 + fg;
        b2[n] = *(const bf16x8*)&Bs[row * 128 + ((c ^ (row & 7)) * 8)];
      }
#pragma unroll
      for (int m = 0; m < 4; m++)
#pragma unroll
        for (int n = 0; n < 4; n++)
          acc[m][n] = __builtin_amdgcn_mfma_f32_16x16x32_bf16(a2[m], b2[n], acc[m][n], 0, 0, 0);
    }

#pragma unroll
    for (int n = 0; n < 4; n++) {
      float wv = wf[nb * 128 + wc * 64 + n * 16 + fr];
#pragma unroll
      for (int m = 0; m < 4; m++)
#pragma unroll
        for (int r = 0; r < 4; r++)
          rs[m][r] += fmaxf(acc[m][n][r], 0.f) * wv;
    }
    __syncthreads();
  }

#pragma unroll
  for (int m = 0; m < 4; m++)
#pragma unroll
    for (int r = 0; r < 4; r++) {
      float v = rs[m][r];
      v += __shfl_xor(v, 1, 64);
      v += __shfl_xor(v, 2, 64);
      v += __shfl_xor(v, 4, 64);
      v += __shfl_xor(v, 8, 64);
      if (fr == 0) atomicAdd(&rowacc[wr * 64 + m * 16 + fg * 4 + r], v);
    }
  __syncthreads();

  if (tid < 128) {
    long row = m0 + tid;
    int bp = (int)(row >> 11), n = (int)(row & 2047);
    if (n < 2000)
      out[(long)bp * 2000 + n] = 10.f * tanhf(rowacc[tid] * 0.08838834764831843f);
  }
}

// ---------------------------------------------------------------------------
extern "C" void kernel_launch(void* const* d_in, const int* in_sizes, int n_in,
                              void* d_out, int out_size, void* d_ws, size_t ws_size,
                              hipStream_t stream) {
  const float* nf    = (const float*)d_in[0];
  const float* H     = (const float*)d_in[1];
  const float* Win   = (const float*)d_in[2];
  const float* edgeW = (const float*)d_in[3];
  const float* nodeW = (const float*)d_in[4];
  const float* W1    = (const float*)d_in[5];
  const float* W2    = (const float*)d_in[6];
  const float* Wdec  = (const float*)d_in[7];
  float* out = (float*)d_out;

  char* ws = (char*)d_ws;
  unsigned short* Hb   = (unsigned short*)(ws + 0);          // 33.55 MB
  unsigned short* HTb  = (unsigned short*)(ws + 33554432);   // 33.55 MB
  unsigned short* xb   = (unsigned short*)(ws + 67108864);   // 16.78 MB
  unsigned short* xTb  = (unsigned short*)(ws + 83886080);   // 16.78 MB
  unsigned short* eTb  = (unsigned short*)(ws + 100663296);  // 16.78 MB
  unsigned short* edgeWT = (unsigned short*)(ws + 117440512);
  unsigned short* nodeWT = (unsigned short*)(ws + 117538816);
  unsigned short* W1T    = (unsigned short*)(ws + 117637120);
  float*          wf     = (float*)(ws + 117768192);
  (void)ws_size; (void)in_sizes; (void)n_in; (void)out_size;

  // ---- input prep ----
  convH_k<<<dim3(64, 64, 4), 256, 0, stream>>>(H, Hb, HTb);
  for (int l = 0; l < 3; l++) {
    transposeW_k<<<dim3(4, 4), 256, 0, stream>>>(edgeW + l * 16384, edgeWT + l * 16384, 128, 128);
    transposeW_k<<<dim3(4, 4), 256, 0, stream>>>(nodeW + l * 16384, nodeWT + l * 16384, 128, 128);
  }
  transposeW_k<<<dim3(16, 4), 256, 0, stream>>>(W1, W1T, 128, 512);
  wfuse_k<<<2, 256, 0, stream>>>(W2, Wdec, wf);
  x0_k<<<dim3(16, 32), 256, 0, stream>>>(nf, Win, xb, xTb);

  // ---- 3 hypergraph layers, 2 fused dispatches each ----
  for (int l = 0; l < 3; l++) {
    // L1: e = relu((H^T @ x) @ We) -> eT
    gemm_fused<0, 1><<<dim3(512), 512, 0, stream>>>(
        HTb, 2048, 2048L * 2048, 8, xTb, 2048, 128L * 2048,
        edgeWT + l * 16384,
        nullptr, 0, 0, eTb, 2048, 128L * 2048, 2048);
    // L2: x = relu((H @ e) @ Wn) -> xT (+ x on last layer for MLP)
    if (l < 2) {
      gemm_fused<0, 1><<<dim3(512), 512, 0, stream>>>(
          Hb, 2048, 2048L * 2048, 8, eTb, 2048, 128L * 2048,
          nodeWT + l * 16384,
          nullptr, 0, 0, xTb, 2048, 128L * 2048, 2048);
    } else {
      gemm_fused<1, 1><<<dim3(512), 512, 0, stream>>>(
          Hb, 2048, 2048L * 2048, 8, eTb, 2048, 128L * 2048,
          nodeWT + l * 16384,
          xb, 128, 2048L * 128, xTb, 2048, 128L * 2048, 2048);
    }
  }

  // ---- fused MLP + decode ----
  mlp_k<<<dim3(512), 256, 0, stream>>>(xb, W1T, wf, out);
}

// Round 11
// 369.204 us; speedup vs baseline: 1.0270x; 1.0270x over previous
//
#include <hip/hip_runtime.h>
#include <hip/hip_bf16.h>

// HypergraphGNN on MI355X (gfx950).
// B=4 P=8 N=E=2000 IN=16 HID=128 NL=3 MULT=4. All f32 inputs; internal bf16 MFMA.
//
// Round-11: heavy GEMM tile 256x128, 4 waves x (128x64) wave-tiles (acc[8][4]).
// Rationale: LDS read bytes/MFMA drop 25% ((128+64) vs (64+64) per 64x... ),
// A staging/HBM amortized over 2x rows. Grid 256 (8 mblk x 32 bz), 1 block/CU,
// LDS 96KB (dbuf 2x48KB; Gs 256x128 bf16 aliases after loop). Schedule =
// round-6 skeleton: static 2-buffer unroll, counted vmcnt(12), setprio MFMA
// clusters, BK=64 chunk^row&7 swizzle (lane-constant read offsets).
// R10 lesson: more waves thrash L2; R7: fragment reads must go via LDS.

typedef __attribute__((ext_vector_type(8))) short bf16x8;
typedef __attribute__((ext_vector_type(4))) float f32x4;

#define GLL16(gp, lp) __builtin_amdgcn_global_load_lds(                      \
    (const __attribute__((address_space(1))) void*)(gp),                     \
    (__attribute__((address_space(3))) void*)(lp), 16, 0, 0)

__device__ __forceinline__ unsigned short f2bf(float v) {
  __hip_bfloat16 h = __float2bfloat16(v);
  return __builtin_bit_cast(unsigned short, h);
}
__device__ __forceinline__ float bf2f(unsigned short u) {
  unsigned int x = ((unsigned int)u) << 16;
  return __builtin_bit_cast(float, x);
}

// ---------------------------------------------------------------------------
// H f32 -> Hb (straight) + HTb (transposed), bf16, padded 2000->2048 w/ zeros
__global__ void convH_k(const float* __restrict__ H,
                        unsigned short* __restrict__ Hb,
                        unsigned short* __restrict__ HTb) {
  int b  = blockIdx.z;
  int n0 = blockIdx.y * 32, e0 = blockIdx.x * 32;
  __shared__ float t[32][33];
  int tx = threadIdx.x & 31, ty = threadIdx.x >> 5;
  for (int r = ty; r < 32; r += 8) {
    int n = n0 + r, e = e0 + tx;
    float v = (n < 2000 && e < 2000) ? H[((long)b * 2000 + n) * 2000 + e] : 0.f;
    t[r][tx] = v;
    Hb[((long)b * 2048 + n) * 2048 + e] = f2bf(v);
  }
  __syncthreads();
  for (int r = ty; r < 32; r += 8) {
    HTb[((long)b * 2048 + (e0 + r)) * 2048 + (n0 + tx)] = f2bf(t[tx][r]);
  }
}

// generic f32 [R][C] -> bf16 [C][R]
__global__ void transposeW_k(const float* __restrict__ src,
                             unsigned short* __restrict__ dst, int R, int C) {
  __shared__ float t[32][33];
  int c0 = blockIdx.x * 32, r0 = blockIdx.y * 32;
  int tx = threadIdx.x & 31, ty = threadIdx.x >> 5;
  for (int rr = ty; rr < 32; rr += 8) {
    int rI = r0 + rr, cI = c0 + tx;
    t[rr][tx] = (rI < R && cI < C) ? src[(long)rI * C + cI] : 0.f;
  }
  __syncthreads();
  for (int rr = ty; rr < 32; rr += 8) {
    int cO = c0 + rr, rO = r0 + tx;
    if (cO < C && rO < R) dst[(long)cO * R + rO] = f2bf(t[tx][rr]);
  }
}

// x0 = nf @ W_in (K=16). Tile: 128 nodes x 128 dims per block.
__global__ __launch_bounds__(256) void x0_k(
    const float* __restrict__ nf, const float* __restrict__ Win,
    unsigned short* __restrict__ xb, unsigned short* __restrict__ xTb) {
  __shared__ float nfs[128][16];
  __shared__ float wins[2048];
  __shared__ unsigned short xt[128][136];

  int bp = blockIdx.y;
  int n0 = blockIdx.x * 128;
  int tid = threadIdx.x;

  {
    int r = tid >> 1, c = (tid & 1) * 8;
    int n = n0 + r;
    float4 v0 = make_float4(0.f, 0.f, 0.f, 0.f), v1 = v0;
    if (n < 2000) {
      const float* src = nf + ((long)bp * 2000 + n) * 16 + c;
      v0 = *(const float4*)src;
      v1 = *(const float4*)(src + 4);
    }
    *(float4*)&nfs[r][c]     = v0;
    *(float4*)&nfs[r][c + 4] = v1;
  }
  {
    int base = tid * 8;
    float4 a = *(const float4*)(Win + base);
    float4 b = *(const float4*)(Win + base + 4);
    *(float4*)&wins[base]     = a;
    *(float4*)&wins[base + 4] = b;
  }
  __syncthreads();

  int d = tid & 127, half = tid >> 7;
  float wcol[16];
#pragma unroll
  for (int k = 0; k < 16; k++) wcol[k] = wins[k * 128 + d];

  unsigned short* xtRow = xTb + ((long)bp * 128 + d) * 2048 + n0 + half * 64;
#pragma unroll
  for (int oct = 0; oct < 8; oct++) {
    bf16x8 pk;
#pragma unroll
    for (int j = 0; j < 8; j++) {
      int nl = half * 64 + oct * 8 + j;
      float v = 0.f;
#pragma unroll
      for (int k = 0; k < 16; k++) v += nfs[nl][k] * wcol[k];
      unsigned short bits = f2bf(v);
      pk[j] = (short)bits;
      xt[nl][d] = bits;
    }
    *(bf16x8*)(xtRow + oct * 8) = pk;
  }
  __syncthreads();

  {
    int r = tid >> 1, c0 = (tid & 1) * 64;
    unsigned short* dst = xb + ((long)bp * 2048 + n0 + r) * 128 + c0;
#pragma unroll
    for (int i = 0; i < 8; i++) {
      bf16x8 v = *(const bf16x8*)&xt[r][c0 + i * 8];
      *(bf16x8*)(dst + i * 8) = v;
    }
  }
}

// wf = W2 @ Wdec  (512x128 @ 128 -> 512)
__global__ void wfuse_k(const float* __restrict__ W2, const float* __restrict__ Wdec,
                        float* __restrict__ wf) {
  int i = blockIdx.x * 256 + threadIdx.x;
  if (i < 512) {
    float s = 0.f;
#pragma unroll 8
    for (int j = 0; j < 128; j++) s += W2[i * 128 + j] * Wdec[j];
    wf[i] = s;
  }
}

// ---------------------------------------------------------------------------
// Fused heavy GEMM: acc = A[2048][K=2048] @ BT[128][K]^T per (m-block, bz),
// then out = relu(acc @ W), Wt[d_out][d_in] global bf16. Writes Cn and/or Ct.
// Tile 256x128, 4 waves x (128x64), BK=64, static dbuf, counted vmcnt(12).
// Grid: 256 blocks 1-D, XCD-swizzled (256%8==0 -> bijective). 256 threads.
template <int WN, int WT>
__global__ __launch_bounds__(256, 1) void gemm_fused(
    const unsigned short* __restrict__ A, int lda, long strideA, int aDiv,
    const unsigned short* __restrict__ BT, int ldbt, long strideBT,
    const unsigned short* __restrict__ Wt,
    unsigned short* __restrict__ Cn, int ldc, long strideCn,
    unsigned short* __restrict__ Ct, int ldct, long strideCt, int K) {
  // XCD decode: XCD c = wgid&7 owns orig [c*32, c*32+32) = 4 bp x 8 mblk
  int wgid = blockIdx.x;
  int orig = (wgid & 7) * 32 + (wgid >> 3);
  int mblk = orig & 7;
  int bz   = orig >> 3;
  A  += (long)(bz / aDiv) * strideA;
  BT += (long)bz * strideBT;
  int m0 = mblk * 256;

  // 96 KB LDS: dbuf sel*24576 shorts = [A 256x64 (16384) | B 128x64 (8192)].
  // Gs (256x128 bf16 = 32768 shorts) aliases [0,32768) after the main loop.
  __shared__ unsigned short smem[49152];

  int tid  = threadIdx.x;
  int lane = tid & 63;
  int w    = tid >> 6;
  int wr   = w >> 1, wc = w & 1;  // wave: rows [wr*128,+128), cols [wc*64,+64)
  int fr   = lane & 15;           // frag row (A) / col (B,C)
  int fg   = lane >> 4;           // k-chunk (inputs) / row-subgroup (C/D)

  // staging: LDS slot linear; global 16B-chunk = slotchunk ^ (row&7)
  int srow   = tid >> 3;                       // 32 rows per issue-group
  int schunk = ((tid & 7) ^ (srow & 7)) * 8;   // element offset (lane-const)
  const unsigned short* Agp[8];
  const unsigned short* Bgp[4];
#pragma unroll
  for (int i = 0; i < 8; i++)
    Agp[i] = A + (long)(m0 + i * 32 + srow) * lda + schunk;
#pragma unroll
  for (int i = 0; i < 4; i++)
    Bgp[i] = BT + (long)(i * 32 + srow) * ldbt + schunk;

#define STAGE(sel, tk) do {                                                  \
    long _k = (long)(tk) * 64;                                               \
    _Pragma("unroll")                                                        \
    for (int i = 0; i < 8; i++)                                              \
      GLL16(Agp[i] + _k, smem + (sel) * 24576 + (i * 256 + tid) * 8);        \
    _Pragma("unroll")                                                        \
    for (int i = 0; i < 4; i++)                                              \
      GLL16(Bgp[i] + _k, smem + (sel) * 24576 + 16384 + (i * 256 + tid) * 8);\
  } while (0)

  f32x4 acc[8][4] = {};
  // lane-constant swizzled read offsets for the two K=32 phases
  const int cOff0 = (fg ^ (fr & 7)) * 8;
  const int cOff1 = ((4 + fg) ^ (fr & 7)) * 8;

#define PHASE(Asp, Bsp, CO) do {                                             \
    bf16x8 af[8], bv[4];                                                     \
    _Pragma("unroll")                                                        \
    for (int m = 0; m < 8; m++)                                              \
      af[m] = *(const bf16x8*)&(Asp)[(wr * 128 + m * 16 + fr) * 64 + (CO)];  \
    _Pragma("unroll")                                                        \
    for (int n = 0; n < 4; n++)                                              \
      bv[n] = *(const bf16x8*)&(Bsp)[(wc * 64 + n * 16 + fr) * 64 + (CO)];   \
    __builtin_amdgcn_s_setprio(1);                                           \
    _Pragma("unroll")                                                        \
    for (int m = 0; m < 8; m++)                                              \
      _Pragma("unroll")                                                      \
      for (int n = 0; n < 4; n++)                                            \
        acc[m][n] = __builtin_amdgcn_mfma_f32_16x16x32_bf16(af[m], bv[n],    \
                                                            acc[m][n], 0, 0, 0); \
    __builtin_amdgcn_s_setprio(0);                                           \
  } while (0)

#define COMPUTE64(sel) do {                                                  \
    const unsigned short* As_ = smem + (sel) * 24576;                        \
    const unsigned short* Bs_ = As_ + 16384;                                 \
    PHASE(As_, Bs_, cOff0);                                                  \
    PHASE(As_, Bs_, cOff1);                                                  \
  } while (0)

#define VMW(n) asm volatile("s_waitcnt vmcnt(" #n ")" ::: "memory")
#define BARR __builtin_amdgcn_s_barrier()
#define SCH0 __builtin_amdgcn_sched_barrier(0)

  int nt2 = K >> 6;  // 32 K-tiles of 64 (even)

  STAGE(0, 0);
  int t = 0;
  for (; t + 2 < nt2; t += 2) {
    STAGE(1, t + 1);
    VMW(12); BARR; SCH0;  // tile t landed; t+1 in flight
    COMPUTE64(0);
    BARR;                 // buf0 free
    STAGE(0, t + 2);
    VMW(12); BARR; SCH0;  // tile t+1 landed; t+2 in flight
    COMPUTE64(1);
    BARR;                 // buf1 free
  }
  STAGE(1, nt2 - 1);
  VMW(12); BARR; SCH0;
  COMPUTE64(0);
  BARR;
  VMW(0); BARR; SCH0;
  COMPUTE64(1);
#undef STAGE
#undef COMPUTE64
#undef PHASE
  __syncthreads();  // all dbuf reads done before Gs aliases it

  // ---- stage-1 acc -> Gs bf16 row-major 256x128, chunk^row&7 swizzle ----
  unsigned short* Gs = smem;
#pragma unroll
  for (int m = 0; m < 8; m++) {
#pragma unroll
    for (int n = 0; n < 4; n++) {
      int rowb = wr * 128 + m * 16 + fg * 4;
      int col  = wc * 64 + n * 16 + fr;
      int ch = col >> 3, ci = col & 7;
#pragma unroll
      for (int r = 0; r < 4; r++) {
        int row = rowb + r;
        Gs[row * 128 + ((ch ^ (row & 7)) * 8) + ci] = f2bf(acc[m][n][r]);
      }
    }
  }
  __syncthreads();

  // ---- stage 2: out = relu(G @ W); A=Gs (256x128), B=Wt global (L2-hot) ----
  f32x4 acc2[8][4] = {};
#pragma unroll
  for (int kk = 0; kk < 4; kk++) {
    bf16x8 a2[8], b2[4];
#pragma unroll
    for (int m = 0; m < 8; m++) {
      int row = wr * 128 + m * 16 + fr;
      int c = kk * 4 + fg;
      a2[m] = *(const bf16x8*)&Gs[row * 128 + ((c ^ (fr & 7)) * 8)];
    }
#pragma unroll
    for (int n = 0; n < 4; n++) {
      int row = wc * 64 + n * 16 + fr;
      b2[n] = *(const bf16x8*)&Wt[row * 128 + (kk * 4 + fg) * 8];
    }
#pragma unroll
    for (int m = 0; m < 8; m++)
#pragma unroll
      for (int n = 0; n < 4; n++)
        acc2[m][n] = __builtin_amdgcn_mfma_f32_16x16x32_bf16(a2[m], b2[n], acc2[m][n], 0, 0, 0);
  }

  // optional normal-layout write (last dispatch only), direct from regs
  if (WN) {
#pragma unroll
    for (int m = 0; m < 8; m++) {
#pragma unroll
      for (int n = 0; n < 4; n++) {
        int rowb = m0 + wr * 128 + m * 16 + fg * 4;
        int col  = wc * 64 + n * 16 + fr;
        unsigned short* p = Cn + bz * strideCn + (long)rowb * ldc + col;
        p[0]       = f2bf(fmaxf(acc2[m][n][0], 0.f));
        p[ldc]     = f2bf(fmaxf(acc2[m][n][1], 0.f));
        p[2 * ldc] = f2bf(fmaxf(acc2[m][n][2], 0.f));
        p[3 * ldc] = f2bf(fmaxf(acc2[m][n][3], 0.f));
      }
    }
  }

  if (WT) {
    // relu'd acc2 -> GsT [col 128][row 256] bf16 (16B-chunk ^ col&7 swizzle),
    // then coalesced 16B stores: Ct row = col, 512B contiguous per row.
    __syncthreads();  // all Gs reads done before overwrite
    unsigned short* GsT = smem;  // 32768 shorts
#pragma unroll
    for (int m = 0; m < 8; m++) {
#pragma unroll
      for (int n = 0; n < 4; n++) {
        int rowb = wr * 128 + m * 16 + fg * 4;  // rowb&7 in {0,4}
        int col  = wc * 64 + n * 16 + fr;
        int slot = (rowb >> 3) ^ (col & 7);
        ushort4 pk;
        pk.x = f2bf(fmaxf(acc2[m][n][0], 0.f));
        pk.y = f2bf(fmaxf(acc2[m][n][1], 0.f));
        pk.z = f2bf(fmaxf(acc2[m][n][2], 0.f));
        pk.w = f2bf(fmaxf(acc2[m][n][3], 0.f));
        *(ushort4*)&GsT[col * 256 + slot * 8 + (rowb & 7)] = pk;
      }
    }
    __syncthreads();
    unsigned short* CtB = Ct + bz * strideCt + m0;
    int col = tid >> 1, halfi = tid & 1;
#pragma unroll
    for (int g = 0; g < 16; g++) {
      int c16 = halfi * 16 + g;          // 16B chunk of the 256-row span
      int slot = c16 ^ (col & 7);
      bf16x8 v = *(const bf16x8*)&GsT[col * 256 + slot * 8];
      *(bf16x8*)(CtB + (long)col * ldct + c16 * 8) = v;
    }
  }
}

// ---------------------------------------------------------------------------
// Fused MLP: out[row] = 10*tanh( (sum_i relu(x@W1)[row][i]*wf[i]) / sqrt(128) )
__global__ __launch_bounds__(256) void mlp_k(
    const unsigned short* __restrict__ X,    // [65536][128] bf16 (padded rows)
    const unsigned short* __restrict__ W1T,  // [512][128] bf16
    const float* __restrict__ wf,            // [512]
    float* __restrict__ out) {
  __shared__ unsigned short Xs[128 * 128];
  __shared__ unsigned short Bs[128 * 128];
  __shared__ float rowacc[128];

  int tid  = threadIdx.x;
  int lane = tid & 63;
  int w    = tid >> 6, wr = w >> 1, wc = w & 1;
  int fr   = lane & 15, fg = lane >> 4;
  long m0  = (long)blockIdx.x * 128;

#pragma unroll
  for (int i = 0; i < 8; i++) {
    int s = i * 256 + tid;
    int r = s >> 4, c = (s & 15) ^ (r & 7);
    GLL16(X + (m0 + r) * 128 + c * 8, (unsigned short*)Xs + s * 8);
  }
  if (tid < 128) rowacc[tid] = 0.f;

  float rs[4][4] = {};

  for (int nb = 0; nb < 4; nb++) {
#pragma unroll
    for (int i = 0; i < 8; i++) {
      int s = i * 256 + tid;
      int r = s >> 4, c = (s & 15) ^ (r & 7);
      GLL16(W1T + (long)(nb * 128 + r) * 128 + c * 8, (unsigned short*)Bs + s * 8);
    }
    __syncthreads();

    f32x4 acc[4][4] = {};
#pragma unroll
    for (int kk = 0; kk < 4; kk++) {
      bf16x8 a2[4], b2[4];
#pragma unroll
      for (int m = 0; m < 4; m++) {
        int row = wr * 64 + m * 16 + fr;
        int c = kk * 4 + fg;
        a2[m] = *(const bf16x8*)&Xs[row * 128 + ((c ^ (row & 7)) * 8)];
      }
#pragma unroll
      for (int n = 0; n < 4; n++) {
        int row = wc * 64 + n * 16 + fr;
        int c = kk * 4 + fg;
        b2[n] = *(const bf16x8*)&Bs[row * 128 + ((c ^ (row & 7)) * 8)];
      }
#pragma unroll
      for (int m = 0; m < 4; m++)
#pragma unroll
        for (int n = 0; n < 4; n++)
          acc[m][n] = __builtin_amdgcn_mfma_f32_16x16x32_bf16(a2[m], b2[n], acc[m][n], 0, 0, 0);
    }

#pragma unroll
    for (int n = 0; n < 4; n++) {
      float wv = wf[nb * 128 + wc * 64 + n * 16 + fr];
#pragma unroll
      for (int m = 0; m < 4; m++)
#pragma unroll
        for (int r = 0; r < 4; r++)
          rs[m][r] += fmaxf(acc[m][n][r], 0.f) * wv;
    }
    __syncthreads();
  }

#pragma unroll
  for (int m = 0; m < 4; m++)
#pragma unroll
    for (int r = 0; r < 4; r++) {
      float v = rs[m][r];
      v += __shfl_xor(v, 1, 64);
      v += __shfl_xor(v, 2, 64);
      v += __shfl_xor(v, 4, 64);
      v += __shfl_xor(v, 8, 64);
      if (fr == 0) atomicAdd(&rowacc[wr * 64 + m * 16 + fg * 4 + r], v);
    }
  __syncthreads();

  if (tid < 128) {
    long row = m0 + tid;
    int bp = (int)(row >> 11), n = (int)(row & 2047);
    if (n < 2000)
      out[(long)bp * 2000 + n] = 10.f * tanhf(rowacc[tid] * 0.08838834764831843f);
  }
}

// ---------------------------------------------------------------------------
extern "C" void kernel_launch(void* const* d_in, const int* in_sizes, int n_in,
                              void* d_out, int out_size, void* d_ws, size_t ws_size,
                              hipStream_t stream) {
  const float* nf    = (const float*)d_in[0];
  const float* H     = (const float*)d_in[1];
  const float* Win   = (const float*)d_in[2];
  const float* edgeW = (const float*)d_in[3];
  const float* nodeW = (const float*)d_in[4];
  const float* W1    = (const float*)d_in[5];
  const float* W2    = (const float*)d_in[6];
  const float* Wdec  = (const float*)d_in[7];
  float* out = (float*)d_out;

  char* ws = (char*)d_ws;
  unsigned short* Hb   = (unsigned short*)(ws + 0);          // 33.55 MB
  unsigned short* HTb  = (unsigned short*)(ws + 33554432);   // 33.55 MB
  unsigned short* xb   = (unsigned short*)(ws + 67108864);   // 16.78 MB
  unsigned short* xTb  = (unsigned short*)(ws + 83886080);   // 16.78 MB
  unsigned short* eTb  = (unsigned short*)(ws + 100663296);  // 16.78 MB
  unsigned short* edgeWT = (unsigned short*)(ws + 117440512);
  unsigned short* nodeWT = (unsigned short*)(ws + 117538816);
  unsigned short* W1T    = (unsigned short*)(ws + 117637120);
  float*          wf     = (float*)(ws + 117768192);
  (void)ws_size; (void)in_sizes; (void)n_in; (void)out_size;

  // ---- input prep ----
  convH_k<<<dim3(64, 64, 4), 256, 0, stream>>>(H, Hb, HTb);
  for (int l = 0; l < 3; l++) {
    transposeW_k<<<dim3(4, 4), 256, 0, stream>>>(edgeW + l * 16384, edgeWT + l * 16384, 128, 128);
    transposeW_k<<<dim3(4, 4), 256, 0, stream>>>(nodeW + l * 16384, nodeWT + l * 16384, 128, 128);
  }
  transposeW_k<<<dim3(16, 4), 256, 0, stream>>>(W1, W1T, 128, 512);
  wfuse_k<<<2, 256, 0, stream>>>(W2, Wdec, wf);
  x0_k<<<dim3(16, 32), 256, 0, stream>>>(nf, Win, xb, xTb);

  // ---- 3 hypergraph layers, 2 fused dispatches each ----
  for (int l = 0; l < 3; l++) {
    // L1: e = relu((H^T @ x) @ We) -> eT
    gemm_fused<0, 1><<<dim3(256), 256, 0, stream>>>(
        HTb, 2048, 2048L * 2048, 8, xTb, 2048, 128L * 2048,
        edgeWT + l * 16384,
        nullptr, 0, 0, eTb, 2048, 128L * 2048, 2048);
    // L2: x = relu((H @ e) @ Wn) -> xT (+ x on last layer for MLP)
    if (l < 2) {
      gemm_fused<0, 1><<<dim3(256), 256, 0, stream>>>(
          Hb, 2048, 2048L * 2048, 8, eTb, 2048, 128L * 2048,
          nodeWT + l * 16384,
          nullptr, 0, 0, xTb, 2048, 128L * 2048, 2048);
    } else {
      gemm_fused<1, 1><<<dim3(256), 256, 0, stream>>>(
          Hb, 2048, 2048L * 2048, 8, eTb, 2048, 128L * 2048,
          nodeWT + l * 16384,
          xb, 128, 2048L * 128, xTb, 2048, 128L * 2048, 2048);
    }
  }

  // ---- fused MLP + decode ----
  mlp_k<<<dim3(512), 256, 0, stream>>>(xb, W1T, wf, out);
}

// Round 12
// 356.391 us; speedup vs baseline: 1.0640x; 1.0360x over previous
//
#include <hip/hip_runtime.h>
#include <hip/hip_bf16.h>

// HypergraphGNN on MI355X (gfx950).
// B=4 P=8 N=E=2000 IN=16 HID=128 NL=3 MULT=4. All f32 inputs; internal bf16 MFMA.
//
// Round-12 heavy GEMM: 8-wave deep-pipelined schedule (m201-style, adapted to
// Nc=128). Tile 256x128, 512 threads = 8 waves of 64x64 (4M x 2N), BK=32,
// ring-4 LDS buffers (4 x 24KB), depth-3 prefetch, ONE barrier per K32 tile,
// counted s_waitcnt vmcnt(6) (never drained in main loop; 2 tiles always in
// flight). setprio around each 16-MFMA cluster (T5 pays with 8-wave
// role-split). Gs (256x128 bf16, 64KB) aliases ring bufs 0-2 in the epilogue.
// Grid 256 blocks (8 mblk x 32 bz), bijective XCD swizzle; 1 block/CU with
// 8 waves (m201 shows deep pipeline makes 1 block/CU fine; R11's failure was
// shallow pipeline, not block count).
// R7 lesson: frag reads must go via LDS. R10: more waves across K thrash L2.
// LDS swizzle (rule #21): linear LDS dest for global_load_lds; global source
// chunk pre-swizzled (chunk ^ ((row>>1)&3), <=2-way = free); reads apply the
// same involution (lane-constant).

typedef __attribute__((ext_vector_type(8))) short bf16x8;
typedef __attribute__((ext_vector_type(4))) float f32x4;

#define GLL16(gp, lp) __builtin_amdgcn_global_load_lds(                      \
    (const __attribute__((address_space(1))) void*)(gp),                     \
    (__attribute__((address_space(3))) void*)(lp), 16, 0, 0)

__device__ __forceinline__ unsigned short f2bf(float v) {
  __hip_bfloat16 h = __float2bfloat16(v);
  return __builtin_bit_cast(unsigned short, h);
}
__device__ __forceinline__ float bf2f(unsigned short u) {
  unsigned int x = ((unsigned int)u) << 16;
  return __builtin_bit_cast(float, x);
}

// ---------------------------------------------------------------------------
// H f32 -> Hb (straight) + HTb (transposed), bf16, padded 2000->2048 w/ zeros
__global__ void convH_k(const float* __restrict__ H,
                        unsigned short* __restrict__ Hb,
                        unsigned short* __restrict__ HTb) {
  int b  = blockIdx.z;
  int n0 = blockIdx.y * 32, e0 = blockIdx.x * 32;
  __shared__ float t[32][33];
  int tx = threadIdx.x & 31, ty = threadIdx.x >> 5;
  for (int r = ty; r < 32; r += 8) {
    int n = n0 + r, e = e0 + tx;
    float v = (n < 2000 && e < 2000) ? H[((long)b * 2000 + n) * 2000 + e] : 0.f;
    t[r][tx] = v;
    Hb[((long)b * 2048 + n) * 2048 + e] = f2bf(v);
  }
  __syncthreads();
  for (int r = ty; r < 32; r += 8) {
    HTb[((long)b * 2048 + (e0 + r)) * 2048 + (n0 + tx)] = f2bf(t[tx][r]);
  }
}

// generic f32 [R][C] -> bf16 [C][R]
__global__ void transposeW_k(const float* __restrict__ src,
                             unsigned short* __restrict__ dst, int R, int C) {
  __shared__ float t[32][33];
  int c0 = blockIdx.x * 32, r0 = blockIdx.y * 32;
  int tx = threadIdx.x & 31, ty = threadIdx.x >> 5;
  for (int rr = ty; rr < 32; rr += 8) {
    int rI = r0 + rr, cI = c0 + tx;
    t[rr][tx] = (rI < R && cI < C) ? src[(long)rI * C + cI] : 0.f;
  }
  __syncthreads();
  for (int rr = ty; rr < 32; rr += 8) {
    int cO = c0 + rr, rO = r0 + tx;
    if (cO < C && rO < R) dst[(long)cO * R + rO] = f2bf(t[tx][rr]);
  }
}

// x0 = nf @ W_in (K=16). Tile: 128 nodes x 128 dims per block.
__global__ __launch_bounds__(256) void x0_k(
    const float* __restrict__ nf, const float* __restrict__ Win,
    unsigned short* __restrict__ xb, unsigned short* __restrict__ xTb) {
  __shared__ float nfs[128][16];
  __shared__ float wins[2048];
  __shared__ unsigned short xt[128][136];

  int bp = blockIdx.y;
  int n0 = blockIdx.x * 128;
  int tid = threadIdx.x;

  {
    int r = tid >> 1, c = (tid & 1) * 8;
    int n = n0 + r;
    float4 v0 = make_float4(0.f, 0.f, 0.f, 0.f), v1 = v0;
    if (n < 2000) {
      const float* src = nf + ((long)bp * 2000 + n) * 16 + c;
      v0 = *(const float4*)src;
      v1 = *(const float4*)(src + 4);
    }
    *(float4*)&nfs[r][c]     = v0;
    *(float4*)&nfs[r][c + 4] = v1;
  }
  {
    int base = tid * 8;
    float4 a = *(const float4*)(Win + base);
    float4 b = *(const float4*)(Win + base + 4);
    *(float4*)&wins[base]     = a;
    *(float4*)&wins[base + 4] = b;
  }
  __syncthreads();

  int d = tid & 127, half = tid >> 7;
  float wcol[16];
#pragma unroll
  for (int k = 0; k < 16; k++) wcol[k] = wins[k * 128 + d];

  unsigned short* xtRow = xTb + ((long)bp * 128 + d) * 2048 + n0 + half * 64;
#pragma unroll
  for (int oct = 0; oct < 8; oct++) {
    bf16x8 pk;
#pragma unroll
    for (int j = 0; j < 8; j++) {
      int nl = half * 64 + oct * 8 + j;
      float v = 0.f;
#pragma unroll
      for (int k = 0; k < 16; k++) v += nfs[nl][k] * wcol[k];
      unsigned short bits = f2bf(v);
      pk[j] = (short)bits;
      xt[nl][d] = bits;
    }
    *(bf16x8*)(xtRow + oct * 8) = pk;
  }
  __syncthreads();

  {
    int r = tid >> 1, c0 = (tid & 1) * 64;
    unsigned short* dst = xb + ((long)bp * 2048 + n0 + r) * 128 + c0;
#pragma unroll
    for (int i = 0; i < 8; i++) {
      bf16x8 v = *(const bf16x8*)&xt[r][c0 + i * 8];
      *(bf16x8*)(dst + i * 8) = v;
    }
  }
}

// wf = W2 @ Wdec  (512x128 @ 128 -> 512)
__global__ void wfuse_k(const float* __restrict__ W2, const float* __restrict__ Wdec,
                        float* __restrict__ wf) {
  int i = blockIdx.x * 256 + threadIdx.x;
  if (i < 512) {
    float s = 0.f;
#pragma unroll 8
    for (int j = 0; j < 128; j++) s += W2[i * 128 + j] * Wdec[j];
    wf[i] = s;
  }
}

// ---------------------------------------------------------------------------
// Fused heavy GEMM: acc = A[2048][K=2048] @ BT[128][K]^T per (m-block, bz),
// then out = relu(acc @ W), Wt[d_out][d_in] global bf16. Writes Cn and/or Ct.
// Tile 256x128, 8 waves x (64x64), BK=32, ring-4 LDS, depth-3 prefetch,
// one barrier + counted vmcnt(6) per tile. Grid 256, XCD-swizzled, 512 thr.
// Requires K % 128 == 0 (nt multiple of 4).
template <int WN, int WT>
__global__ __launch_bounds__(512, 1) void gemm_fused(
    const unsigned short* __restrict__ A, int lda, long strideA, int aDiv,
    const unsigned short* __restrict__ BT, int ldbt, long strideBT,
    const unsigned short* __restrict__ Wt,
    unsigned short* __restrict__ Cn, int ldc, long strideCn,
    unsigned short* __restrict__ Ct, int ldct, long strideCt, int K) {
  // XCD decode: XCD c = wgid&7 owns orig [c*32, c*32+32) = 4 bz x 8 mblk
  int wgid = blockIdx.x;
  int orig = (wgid & 7) * 32 + (wgid >> 3);
  int mblk = orig & 7;
  int bz   = orig >> 3;
  A  += (long)(bz / aDiv) * strideA;
  BT += (long)bz * strideBT;
  int m0 = mblk * 256;

  // 96 KB LDS: ring-4 bufs of 12288 shorts = [A 256x32 (8192) | B 128x32 (4096)].
  // Gs (256x128 bf16 = 32768 shorts = 64KB) aliases bufs 0-2 after the loop.
  __shared__ unsigned short smem[49152];

  int tid  = threadIdx.x;
  int lane = tid & 63;
  int w    = tid >> 6;          // 0..7
  int wr   = w >> 1;            // 0..3 -> rows [wr*64, +64)
  int wc   = w & 1;             // 0..1 -> cols [wc*64, +64)
  int fr   = lane & 15;         // frag row (A) / col (B,C)
  int fg   = lane >> 4;         // k-chunk (inputs) / row-subgroup (C/D)

  // staging: per tile 3 gloads/thread (A rows 0-127, A rows 128-255, B).
  // LDS dest linear; global 16B-chunk = slot ^ ((row>>1)&3).
  int srow = tid >> 2;                            // 0..127
  int sch  = ((tid & 3) ^ ((srow >> 1) & 3)) * 8; // element offset, lane-const
  const unsigned short* Ag0 = A + (long)(m0 + srow) * lda + sch;
  const unsigned short* Ag1 = A + (long)(m0 + 128 + srow) * lda + sch;
  const unsigned short* Bg  = BT + (long)srow * ldbt + sch;

#define STAGE(sel, tk) do {                                                  \
    int _k = (tk) * 32;                                                      \
    GLL16(Ag0 + _k, smem + (sel) * 12288 + tid * 8);                         \
    GLL16(Ag1 + _k, smem + (sel) * 12288 + 4096 + tid * 8);                  \
    GLL16(Bg + _k,  smem + (sel) * 12288 + 8192 + tid * 8);                  \
  } while (0)

  f32x4 acc[4][4] = {};
  const int cIdx = (fg ^ ((fr >> 1) & 3)) * 8;  // swizzled frag offset

  // One tile: ds_read 8 frags, optional STAGE(t+3), setprio'd 16-MFMA cluster.
#define TILEBODY(sel, kst, DO) do {                                          \
    const unsigned short* As_ = smem + (sel) * 12288;                        \
    const unsigned short* Bs_ = As_ + 8192;                                  \
    bf16x8 af[4], bv[4];                                                     \
    _Pragma("unroll")                                                        \
    for (int m = 0; m < 4; m++)                                              \
      af[m] = *(const bf16x8*)&As_[(wr * 64 + m * 16 + fr) * 32 + cIdx];     \
    _Pragma("unroll")                                                        \
    for (int n = 0; n < 4; n++)                                              \
      bv[n] = *(const bf16x8*)&Bs_[(wc * 64 + n * 16 + fr) * 32 + cIdx];     \
    if (DO) STAGE(((sel) + 3) & 3, kst);                                     \
    __builtin_amdgcn_s_setprio(1);                                           \
    _Pragma("unroll")                                                        \
    for (int m = 0; m < 4; m++)                                              \
      _Pragma("unroll")                                                      \
      for (int n = 0; n < 4; n++)                                            \
        acc[m][n] = __builtin_amdgcn_mfma_f32_16x16x32_bf16(af[m], bv[n],    \
                                                            acc[m][n], 0, 0, 0); \
    __builtin_amdgcn_s_setprio(0);                                           \
  } while (0)

#define VMW(n) asm volatile("s_waitcnt vmcnt(" #n ")" ::: "memory")
#define BARR __builtin_amdgcn_s_barrier()
#define SCH0 __builtin_amdgcn_sched_barrier(0)

  int nt = K >> 5;  // 64 K-tiles of 32 (multiple of 4)

  // prologue: depth-3 prefetch (9 loads/thread in flight)
  STAGE(0, 0);
  STAGE(1, 1);
  STAGE(2, 2);
  // main loop: per tile {VMW(6); barrier; reads+stage+MFMA}. vmcnt never
  // drains below 2 tiles in flight.
  int k = 0;
  for (; k < nt - 4; k += 4) {
    VMW(6); BARR; SCH0; TILEBODY(0, k + 3, 1);
    VMW(6); BARR; SCH0; TILEBODY(1, k + 4, 1);
    VMW(6); BARR; SCH0; TILEBODY(2, k + 5, 1);
    VMW(6); BARR; SCH0; TILEBODY(3, k + 6, 1);
  }
  // epilogue: tiles nt-4..nt-1 (k == nt-4, multiple of 4 -> bufs 0..3)
  VMW(6); BARR; SCH0; TILEBODY(0, nt - 1, 1);  // stages last tile
  VMW(6); BARR; SCH0; TILEBODY(1, 0, 0);
  VMW(3); BARR; SCH0; TILEBODY(2, 0, 0);
  VMW(0); BARR; SCH0; TILEBODY(3, 0, 0);
#undef STAGE
#undef TILEBODY
  __syncthreads();  // all ring reads done before Gs aliases bufs 0-2

  // ---- stage-1 acc -> Gs bf16 row-major 256x128, chunk^row&7 swizzle ----
  unsigned short* Gs = smem;
#pragma unroll
  for (int m = 0; m < 4; m++) {
#pragma unroll
    for (int n = 0; n < 4; n++) {
      int rowb = wr * 64 + m * 16 + fg * 4;
      int col  = wc * 64 + n * 16 + fr;
      int ch = col >> 3, ci = col & 7;
#pragma unroll
      for (int r = 0; r < 4; r++) {
        int row = rowb + r;
        Gs[row * 128 + ((ch ^ (row & 7)) * 8) + ci] = f2bf(acc[m][n][r]);
      }
    }
  }
  __syncthreads();

  // ---- stage 2: out = relu(G @ W); A=Gs (256x128), B=Wt global (L2-hot) ----
  f32x4 acc2[4][4] = {};
#pragma unroll
  for (int kk = 0; kk < 4; kk++) {
    bf16x8 a2[4], b2[4];
#pragma unroll
    for (int m = 0; m < 4; m++) {
      int row = wr * 64 + m * 16 + fr;
      int c = kk * 4 + fg;
      a2[m] = *(const bf16x8*)&Gs[row * 128 + ((c ^ (fr & 7)) * 8)];
    }
#pragma unroll
    for (int n = 0; n < 4; n++) {
      int row = wc * 64 + n * 16 + fr;
      b2[n] = *(const bf16x8*)&Wt[row * 128 + (kk * 4 + fg) * 8];
    }
#pragma unroll
    for (int m = 0; m < 4; m++)
#pragma unroll
      for (int n = 0; n < 4; n++)
        acc2[m][n] = __builtin_amdgcn_mfma_f32_16x16x32_bf16(a2[m], b2[n], acc2[m][n], 0, 0, 0);
  }

  // optional normal-layout write (last dispatch only), direct from regs
  if (WN) {
#pragma unroll
    for (int m = 0; m < 4; m++) {
#pragma unroll
      for (int n = 0; n < 4; n++) {
        int rowb = m0 + wr * 64 + m * 16 + fg * 4;
        int col  = wc * 64 + n * 16 + fr;
        unsigned short* p = Cn + bz * strideCn + (long)rowb * ldc + col;
        p[0]       = f2bf(fmaxf(acc2[m][n][0], 0.f));
        p[ldc]     = f2bf(fmaxf(acc2[m][n][1], 0.f));
        p[2 * ldc] = f2bf(fmaxf(acc2[m][n][2], 0.f));
        p[3 * ldc] = f2bf(fmaxf(acc2[m][n][3], 0.f));
      }
    }
  }

  if (WT) {
    // relu'd acc2 -> GsT [col 128][row 256] bf16 (8elem-slot ^ col&7 swizzle),
    // then coalesced 16B stores: Ct row = col, 512B contiguous per row.
    __syncthreads();  // all Gs reads done before overwrite
    unsigned short* GsT = smem;  // 32768 shorts
#pragma unroll
    for (int m = 0; m < 4; m++) {
#pragma unroll
      for (int n = 0; n < 4; n++) {
        int rowb = wr * 64 + m * 16 + fg * 4;  // rowb&7 in {0,4}
        int col  = wc * 64 + n * 16 + fr;
        int slot = (rowb >> 3) ^ (col & 7);
        ushort4 pk;
        pk.x = f2bf(fmaxf(acc2[m][n][0], 0.f));
        pk.y = f2bf(fmaxf(acc2[m][n][1], 0.f));
        pk.z = f2bf(fmaxf(acc2[m][n][2], 0.f));
        pk.w = f2bf(fmaxf(acc2[m][n][3], 0.f));
        *(ushort4*)&GsT[col * 256 + slot * 8 + (rowb & 7)] = pk;
      }
    }
    __syncthreads();
    unsigned short* CtB = Ct + bz * strideCt + m0;
    int col = tid >> 2, q = tid & 3;
#pragma unroll
    for (int g = 0; g < 8; g++) {
      int c16 = q * 8 + g;               // 16B chunk of the 256-row span
      int slot = c16 ^ (col & 7);
      bf16x8 v = *(const bf16x8*)&GsT[col * 256 + slot * 8];
      *(bf16x8*)(CtB + (long)col * ldct + c16 * 8) = v;
    }
  }
}

// ---------------------------------------------------------------------------
// Fused MLP: out[row] = 10*tanh( (sum_i relu(x@W1)[row][i]*wf[i]) / sqrt(128) )
__global__ __launch_bounds__(256) void mlp_k(
    const unsigned short* __restrict__ X,    // [65536][128] bf16 (padded rows)
    const unsigned short* __restrict__ W1T,  // [512][128] bf16
    const float* __restrict__ wf,            // [512]
    float* __restrict__ out) {
  __shared__ unsigned short Xs[128 * 128];
  __shared__ unsigned short Bs[128 * 128];
  __shared__ float rowacc[128];

  int tid  = threadIdx.x;
  int lane = tid & 63;
  int w    = tid >> 6, wr = w >> 1, wc = w & 1;
  int fr   = lane & 15, fg = lane >> 4;
  long m0  = (long)blockIdx.x * 128;

#pragma unroll
  for (int i = 0; i < 8; i++) {
    int s = i * 256 + tid;
    int r = s >> 4, c = (s & 15) ^ (r & 7);
    GLL16(X + (m0 + r) * 128 + c * 8, (unsigned short*)Xs + s * 8);
  }
  if (tid < 128) rowacc[tid] = 0.f;

  float rs[4][4] = {};

  for (int nb = 0; nb < 4; nb++) {
#pragma unroll
    for (int i = 0; i < 8; i++) {
      int s = i * 256 + tid;
      int r = s >> 4, c = (s & 15) ^ (r & 7);
      GLL16(W1T + (long)(nb * 128 + r) * 128 + c * 8, (unsigned short*)Bs + s * 8);
    }
    __syncthreads();

    f32x4 acc[4][4] = {};
#pragma unroll
    for (int kk = 0; kk < 4; kk++) {
      bf16x8 a2[4], b2[4];
#pragma unroll
      for (int m = 0; m < 4; m++) {
        int row = wr * 64 + m * 16 + fr;
        int c = kk * 4 + fg;
        a2[m] = *(const bf16x8*)&Xs[row * 128 + ((c ^ (row & 7)) * 8)];
      }
#pragma unroll
      for (int n = 0; n < 4; n++) {
        int row = wc * 64 + n * 16 + fr;
        int c = kk * 4 + fg;
        b2[n] = *(const bf16x8*)&Bs[row * 128 + ((c ^ (row & 7)) * 8)];
      }
#pragma unroll
      for (int m = 0; m < 4; m++)
#pragma unroll
        for (int n = 0; n < 4; n++)
          acc[m][n] = __builtin_amdgcn_mfma_f32_16x16x32_bf16(a2[m], b2[n], acc[m][n], 0, 0, 0);
    }

#pragma unroll
    for (int n = 0; n < 4; n++) {
      float wv = wf[nb * 128 + wc * 64 + n * 16 + fr];
#pragma unroll
      for (int m = 0; m < 4; m++)
#pragma unroll
        for (int r = 0; r < 4; r++)
          rs[m][r] += fmaxf(acc[m][n][r], 0.f) * wv;
    }
    __syncthreads();
  }

#pragma unroll
  for (int m = 0; m < 4; m++)
#pragma unroll
    for (int r = 0; r < 4; r++) {
      float v = rs[m][r];
      v += __shfl_xor(v, 1, 64);
      v += __shfl_xor(v, 2, 64);
      v += __shfl_xor(v, 4, 64);
      v += __shfl_xor(v, 8, 64);
      if (fr == 0) atomicAdd(&rowacc[wr * 64 + m * 16 + fg * 4 + r], v);
    }
  __syncthreads();

  if (tid < 128) {
    long row = m0 + tid;
    int bp = (int)(row >> 11), n = (int)(row & 2047);
    if (n < 2000)
      out[(long)bp * 2000 + n] = 10.f * tanhf(rowacc[tid] * 0.08838834764831843f);
  }
}

// ---------------------------------------------------------------------------
extern "C" void kernel_launch(void* const* d_in, const int* in_sizes, int n_in,
                              void* d_out, int out_size, void* d_ws, size_t ws_size,
                              hipStream_t stream) {
  const float* nf    = (const float*)d_in[0];
  const float* H     = (const float*)d_in[1];
  const float* Win   = (const float*)d_in[2];
  const float* edgeW = (const float*)d_in[3];
  const float* nodeW = (const float*)d_in[4];
  const float* W1    = (const float*)d_in[5];
  const float* W2    = (const float*)d_in[6];
  const float* Wdec  = (const float*)d_in[7];
  float* out = (float*)d_out;

  char* ws = (char*)d_ws;
  unsigned short* Hb   = (unsigned short*)(ws + 0);          // 33.55 MB
  unsigned short* HTb  = (unsigned short*)(ws + 33554432);   // 33.55 MB
  unsigned short* xb   = (unsigned short*)(ws + 67108864);   // 16.78 MB
  unsigned short* xTb  = (unsigned short*)(ws + 83886080);   // 16.78 MB
  unsigned short* eTb  = (unsigned short*)(ws + 100663296);  // 16.78 MB
  unsigned short* edgeWT = (unsigned short*)(ws + 117440512);
  unsigned short* nodeWT = (unsigned short*)(ws + 117538816);
  unsigned short* W1T    = (unsigned short*)(ws + 117637120);
  float*          wf     = (float*)(ws + 117768192);
  (void)ws_size; (void)in_sizes; (void)n_in; (void)out_size;

  // ---- input prep ----
  convH_k<<<dim3(64, 64, 4), 256, 0, stream>>>(H, Hb, HTb);
  for (int l = 0; l < 3; l++) {
    transposeW_k<<<dim3(4, 4), 256, 0, stream>>>(edgeW + l * 16384, edgeWT + l * 16384, 128, 128);
    transposeW_k<<<dim3(4, 4), 256, 0, stream>>>(nodeW + l * 16384, nodeWT + l * 16384, 128, 128);
  }
  transposeW_k<<<dim3(16, 4), 256, 0, stream>>>(W1, W1T, 128, 512);
  wfuse_k<<<2, 256, 0, stream>>>(W2, Wdec, wf);
  x0_k<<<dim3(16, 32), 256, 0, stream>>>(nf, Win, xb, xTb);

  // ---- 3 hypergraph layers, 2 fused dispatches each ----
  for (int l = 0; l < 3; l++) {
    // L1: e = relu((H^T @ x) @ We) -> eT
    gemm_fused<0, 1><<<dim3(256), 512, 0, stream>>>(
        HTb, 2048, 2048L * 2048, 8, xTb, 2048, 128L * 2048,
        edgeWT + l * 16384,
        nullptr, 0, 0, eTb, 2048, 128L * 2048, 2048);
    // L2: x = relu((H @ e) @ Wn) -> xT (+ x on last layer for MLP)
    if (l < 2) {
      gemm_fused<0, 1><<<dim3(256), 512, 0, stream>>>(
          Hb, 2048, 2048L * 2048, 8, eTb, 2048, 128L * 2048,
          nodeWT + l * 16384,
          nullptr, 0, 0, xTb, 2048, 128L * 2048, 2048);
    } else {
      gemm_fused<1, 1><<<dim3(256), 512, 0, stream>>>(
          Hb, 2048, 2048L * 2048, 8, eTb, 2048, 128L * 2048,
          nodeWT + l * 16384,
          xb, 128, 2048L * 128, xTb, 2048, 128L * 2048, 2048);
    }
  }

  // ---- fused MLP + decode ----
  mlp_k<<<dim3(512), 256, 0, stream>>>(xb, W1T, wf, out);
}